// Round 1
// baseline (9242.156 us; speedup 1.0000x reference)
//
#include <hip/hip_runtime.h>
#include <hip/hip_bf16.h>

#define DIM 896
#define TT 4096
#define BB 8
#define NS 64           // slots
#define NCHUNK 16       // 4096/256
#define CH 256          // chunk length

typedef float floatx4 __attribute__((ext_vector_type(4)));
typedef short short8 __attribute__((ext_vector_type(8)));

// ---------------- K0: per-token dots  R = h.Wnm1, P2 = h.Wnm2, Q = h.Wwg1 ----------------
__global__ __launch_bounds__(64) void k0_dots(const float* __restrict__ h,
                                              const float* __restrict__ W_nm,
                                              const float* __restrict__ W_wg,
                                              float* __restrict__ R, float* __restrict__ Q,
                                              float* __restrict__ P2) {
    const int r = blockIdx.x;
    const int lane = threadIdx.x;
    const float* hr = h + (size_t)r * DIM;
    float a = 0.f, bsum = 0.f, c = 0.f;
    for (int k = lane; k < DIM; k += 64) {
        float hv = hr[k];
        a = fmaf(hv, W_nm[k], a);
        bsum = fmaf(hv, W_nm[DIM + k], bsum);
        c = fmaf(hv, W_wg[k], c);
    }
    #pragma unroll
    for (int off = 32; off; off >>= 1) {
        a += __shfl_xor(a, off);
        bsum += __shfl_xor(bsum, off);
        c += __shfl_xor(c, off);
    }
    if (lane == 0) { R[r] = a; P2[r] = bsum; Q[r] = c; }
}

// ---------------- K1: sequential scan (one block per batch) ----------------
// 1024 threads: thread = slot s (tid>>4) x j (tid&15); each owns 56 dims of mem[s].
// Records: fbuf (attn rows), wgbuf, ssbuf, snap (state every 256 steps).
__global__ __launch_bounds__(1024) void k1_scan(const float* __restrict__ h,
                                                const int* __restrict__ mask,
                                                const float* __restrict__ W_wg,
                                                const float* __restrict__ b_nm,
                                                const float* __restrict__ b_wg,
                                                const float* __restrict__ R,
                                                const float* __restrict__ Q,
                                                const float* __restrict__ P2,
                                                float* __restrict__ fbuf,
                                                float* __restrict__ wgbuf,
                                                int* __restrict__ ssbuf,
                                                float* __restrict__ snap) {
    const int b = blockIdx.x;
    const int tid = threadIdx.x;
    const int s = tid >> 4;
    const int j = tid & 15;
    const int lane = tid & 63;

    __shared__ float hbuf[2][16 * 60];   // padded stride 60 floats per j-chunk
    __shared__ float scores_lds[NS];
    __shared__ float bc[2];

    float mem[56];
    #pragma unroll
    for (int i = 0; i < 56; i++) mem[i] = 0.f;
    float Kreg = 0.f;   // wave0 lane s: mem[s] . Wnm2

    const float scale = 1.0f / sqrtf((float)DIM);
    const float bnm = b_nm[0], bwg = b_wg[0], wwgD = W_wg[DIM];
    const size_t hb = (size_t)b * TT * DIM;

    const int jj = tid / 56;
    const int ii = tid - jj * 56;

    float hreg = 0.f;
    if (tid < DIM) { hreg = h[hb + tid]; hbuf[0][jj * 60 + ii] = hreg; }

    float Rbt = 0.f, Qbt = 0.f, P2bt = 0.f, keepf = 0.f;
    if (tid < 64) {
        Rbt = R[b * TT]; Qbt = Q[b * TT]; P2bt = P2[b * TT];
        keepf = (float)mask[b * TT];
    }
    __syncthreads();

    for (int t = 0; t < TT; ++t) {
        const int cur = t & 1;
        // issue next h load early (latency hidden behind the step)
        if (tid < DIM) {
            int tn = (t + 1 < TT) ? (t + 1) : t;
            hreg = h[hb + (size_t)tn * DIM + tid];
        }
        // snapshot state at chunk starts (pre-update state for step t)
        if ((t & (CH - 1)) == 0) {
            float* sp = snap + (((size_t)b * NCHUNK + (t >> 8)) * NS + s) * DIM + j * 56;
            #pragma unroll
            for (int i = 0; i < 14; i++) {
                float4 v = make_float4(mem[4 * i], mem[4 * i + 1], mem[4 * i + 2], mem[4 * i + 3]);
                *(float4*)(sp + 4 * i) = v;
            }
        }
        // ---- scores ----
        const float4* hb4 = (const float4*)&hbuf[cur][j * 60];
        float p = 0.f;
        #pragma unroll
        for (int i = 0; i < 14; i++) {
            float4 hv = hb4[i];
            p = fmaf(mem[4 * i], hv.x, p);
            p = fmaf(mem[4 * i + 1], hv.y, p);
            p = fmaf(mem[4 * i + 2], hv.z, p);
            p = fmaf(mem[4 * i + 3], hv.w, p);
        }
        p += __shfl_xor(p, 1); p += __shfl_xor(p, 2);
        p += __shfl_xor(p, 4); p += __shfl_xor(p, 8);
        if (j == 0) scores_lds[s] = p * scale;
        __syncthreads();

        // ---- softmax / argmax / gates (wave 0 only) ----
        if (tid < 64) {
            float sc = scores_lds[lane];
            float mv = sc; int mi = lane;
            #pragma unroll
            for (int off = 1; off < 64; off <<= 1) {
                float ov = __shfl_xor(mv, off);
                int oi = __shfl_xor(mi, off);
                if (ov > mv || (ov == mv && oi < mi)) { mv = ov; mi = oi; }
            }
            float e = __expf(sc - mv);
            float se = e, sk = e * Kreg;
            #pragma unroll
            for (int off = 1; off < 64; off <<= 1) {
                se += __shfl_xor(se, off);
                sk += __shfl_xor(sk, off);
            }
            float inv = 1.0f / se;
            float a = e * inv;
            float gdot = sk * inv;
            float g = 1.0f / (1.0f + __expf(-(Rbt + gdot + bnm)));
            float w = 1.0f / (1.0f + __expf(-(Qbt + g * wwgD + bwg)));
            w = fminf(fmaxf(w, 0.0f), 0.2f) * keepf;
            fbuf[((size_t)b * TT + t) * NS + lane] = a;
            if (lane == 0) {
                wgbuf[b * TT + t] = w;
                ssbuf[b * TT + t] = mi;
                bc[0] = __int_as_float(mi);
                bc[1] = w;
            }
            if (lane == mi) Kreg = fmaf(Kreg, 1.0f - w, w * P2bt);
            // prefetch next-step scalars
            int tn = (t + 1 < TT) ? (t + 1) : t;
            Rbt = R[b * TT + tn]; Qbt = Q[b * TT + tn]; P2bt = P2[b * TT + tn];
            keepf = (float)mask[b * TT + tn];
        }
        __syncthreads();

        // ---- state update (only the argmax slot's 16 threads do work) ----
        {
            int mi = __float_as_int(bc[0]);
            float w = bc[1];
            if (s == mi) {
                float om = 1.0f - w;
                #pragma unroll
                for (int i = 0; i < 14; i++) {
                    float4 hv = hb4[i];
                    mem[4 * i]     = fmaf(mem[4 * i],     om, w * hv.x);
                    mem[4 * i + 1] = fmaf(mem[4 * i + 1], om, w * hv.y);
                    mem[4 * i + 2] = fmaf(mem[4 * i + 2], om, w * hv.z);
                    mem[4 * i + 3] = fmaf(mem[4 * i + 3], om, w * hv.w);
                }
            }
        }
        if (tid < DIM) hbuf[cur ^ 1][jj * 60 + ii] = hreg;
        __syncthreads();
    }
}

// ---------------- K2: chunk-parallel replay -> m_t (bf16) ----------------
// One block per (batch, chunk); 896 threads = dims; mem[64] per thread in regs.
#define CS_(i) case i: mem[i] = fmaf(mem[i], sA, aB); break;
__global__ __launch_bounds__(896) void k2_replay(const float* __restrict__ h,
                                                 const float* __restrict__ fbuf,
                                                 const float* __restrict__ wgbuf,
                                                 const int* __restrict__ ssbuf,
                                                 const float* __restrict__ snap,
                                                 __hip_bfloat16* __restrict__ Mbuf) {
    const int blk = blockIdx.x;
    const int b = blk >> 4;
    const int c = blk & 15;
    const int tid = threadIdx.x;   // dim index

    __shared__ float lf[128 * NS];   // half-chunk of attn rows (32 KB)
    __shared__ float lwg[CH];
    __shared__ int   lss[CH];

    float mem[64];
    const float* sp = snap + (((size_t)b * NCHUNK + c) * NS) * DIM + tid;
    #pragma unroll
    for (int s2 = 0; s2 < 64; s2++) mem[s2] = sp[(size_t)s2 * DIM];

    const int t0 = c * CH;
    if (tid < CH) {
        lwg[tid] = wgbuf[b * TT + t0 + tid];
        lss[tid] = ssbuf[b * TT + t0 + tid];
    }
    const size_t hbase = (size_t)b * TT * DIM + (size_t)t0 * DIM + tid;
    const size_t fbase = ((size_t)b * TT + t0) * NS;
    const size_t mrow = ((size_t)b * TT + t0) * DIM + tid;

    for (int half = 0; half < 2; ++half) {
        __syncthreads();
        for (int idx = tid; idx < 128 * NS; idx += 896)
            lf[idx] = fbuf[fbase + (size_t)half * 128 * NS + idx];
        __syncthreads();
        for (int tl = 0; tl < 128; ++tl) {
            const int tt = half * 128 + tl;
            float hval = h[hbase + (size_t)tt * DIM];
            float m = 0.f;
            const float4* f4p = (const float4*)&lf[tl * NS];
            #pragma unroll
            for (int q = 0; q < 16; q++) {
                float4 f4 = f4p[q];
                m = fmaf(f4.x, mem[4 * q], m);
                m = fmaf(f4.y, mem[4 * q + 1], m);
                m = fmaf(f4.z, mem[4 * q + 2], m);
                m = fmaf(f4.w, mem[4 * q + 3], m);
            }
            Mbuf[mrow + (size_t)tt * DIM] = __float2bfloat16(m);
            float w = lwg[tt];
            int ss = lss[tt];
            float sA = 1.0f - w, aB = w * hval;
            switch (ss) {
                CS_(0) CS_(1) CS_(2) CS_(3) CS_(4) CS_(5) CS_(6) CS_(7)
                CS_(8) CS_(9) CS_(10) CS_(11) CS_(12) CS_(13) CS_(14) CS_(15)
                CS_(16) CS_(17) CS_(18) CS_(19) CS_(20) CS_(21) CS_(22) CS_(23)
                CS_(24) CS_(25) CS_(26) CS_(27) CS_(28) CS_(29) CS_(30) CS_(31)
                CS_(32) CS_(33) CS_(34) CS_(35) CS_(36) CS_(37) CS_(38) CS_(39)
                CS_(40) CS_(41) CS_(42) CS_(43) CS_(44) CS_(45) CS_(46) CS_(47)
                CS_(48) CS_(49) CS_(50) CS_(51) CS_(52) CS_(53) CS_(54) CS_(55)
                CS_(56) CS_(57) CS_(58) CS_(59) CS_(60) CS_(61) CS_(62) CS_(63)
            }
        }
    }
}

// ---------------- K3: row LayerNorm in place on Mbuf (bf16) ----------------
__global__ __launch_bounds__(64) void k3_ln(__hip_bfloat16* __restrict__ Mbuf,
                                            const float* __restrict__ ln_g,
                                            const float* __restrict__ ln_b) {
    const size_t r = blockIdx.x;
    const int lane = threadIdx.x;
    __hip_bfloat16* row = Mbuf + r * DIM;
    float v[14];
    float s1 = 0.f, s2 = 0.f;
    #pragma unroll
    for (int i = 0; i < 14; i++) {
        float x = __bfloat162float(row[lane + 64 * i]);
        v[i] = x; s1 += x; s2 = fmaf(x, x, s2);
    }
    #pragma unroll
    for (int off = 32; off; off >>= 1) {
        s1 += __shfl_xor(s1, off);
        s2 += __shfl_xor(s2, off);
    }
    float mu = s1 * (1.0f / DIM);
    float var = fmaxf(s2 * (1.0f / DIM) - mu * mu, 0.0f);
    float rs = 1.0f / sqrtf(var + 1e-5f);
    #pragma unroll
    for (int i = 0; i < 14; i++) {
        int d = lane + 64 * i;
        row[d] = __float2bfloat16((v[i] - mu) * rs * ln_g[d] + ln_b[d]);
    }
}

// ---------------- K4: out = h + clip(0.5 * MN @ W_out^T) (bf16 MFMA GEMM) ----------------
__global__ __launch_bounds__(256) void k4_gemm(const __hip_bfloat16* __restrict__ Mn,
                                               const float* __restrict__ W_out,
                                               const float* __restrict__ h,
                                               float* __restrict__ out) {
    const int nt = blockIdx.x;   // 0..6
    const int mt = blockIdx.y;   // 0..255
    const int tid = threadIdx.x;
    const int wave = tid >> 6, lane = tid & 63;
    const int wr = wave >> 1, wc = wave & 1;

    __shared__ __hip_bfloat16 Asb[128 * 72];
    __shared__ __hip_bfloat16 Bsb[128 * 72];   // Bsb[n][k] = W_out[nG][kG]

    floatx4 acc[4][4];
    #pragma unroll
    for (int i = 0; i < 4; i++)
        #pragma unroll
        for (int jn = 0; jn < 4; jn++)
            acc[i][jn] = (floatx4){0.f, 0.f, 0.f, 0.f};

    const int lrow = lane & 15;
    const int lk = (lane >> 4) * 8;
    const int rr = tid >> 3, ch = tid & 7;

    for (int kt = 0; kt < 14; ++kt) {
        #pragma unroll
        for (int it = 0; it < 4; ++it) {
            int row = rr + 32 * it;
            const uint4* srcA = (const uint4*)(Mn + ((size_t)(mt * 128 + row)) * DIM + kt * 64 + ch * 8);
            *(uint4*)&Asb[row * 72 + ch * 8] = *srcA;
            const float* srcB = W_out + ((size_t)(nt * 128 + row)) * DIM + kt * 64 + ch * 8;
            float4 f0 = *(const float4*)srcB;
            float4 f1 = *(const float4*)(srcB + 4);
            alignas(16) __hip_bfloat16 tmp[8];
            tmp[0] = __float2bfloat16(f0.x); tmp[1] = __float2bfloat16(f0.y);
            tmp[2] = __float2bfloat16(f0.z); tmp[3] = __float2bfloat16(f0.w);
            tmp[4] = __float2bfloat16(f1.x); tmp[5] = __float2bfloat16(f1.y);
            tmp[6] = __float2bfloat16(f1.z); tmp[7] = __float2bfloat16(f1.w);
            *(uint4*)&Bsb[row * 72 + ch * 8] = *(uint4*)tmp;
        }
        __syncthreads();
        #pragma unroll
        for (int kk = 0; kk < 2; ++kk) {
            short8 af[4], bfr[4];
            #pragma unroll
            for (int i = 0; i < 4; i++)
                af[i] = *(const short8*)&Asb[(wr * 64 + i * 16 + lrow) * 72 + kk * 32 + lk];
            #pragma unroll
            for (int i2 = 0; i2 < 4; i2++)
                bfr[i2] = *(const short8*)&Bsb[(wc * 64 + i2 * 16 + lrow) * 72 + kk * 32 + lk];
            #pragma unroll
            for (int i = 0; i < 4; i++)
                #pragma unroll
                for (int jn = 0; jn < 4; jn++)
                    acc[i][jn] = __builtin_amdgcn_mfma_f32_16x16x32_bf16(af[i], bfr[jn], acc[i][jn], 0, 0, 0);
        }
        __syncthreads();
    }
    const int crow = (lane >> 4) * 4, ccol = lane & 15;
    #pragma unroll
    for (int i = 0; i < 4; i++)
        #pragma unroll
        for (int jn = 0; jn < 4; jn++)
            #pragma unroll
            for (int rg = 0; rg < 4; rg++) {
                int rG = mt * 128 + wr * 64 + i * 16 + crow + rg;
                int nG = nt * 128 + wc * 64 + jn * 16 + ccol;
                size_t idx = (size_t)rG * DIM + nG;
                float d = acc[i][jn][rg] * 0.5f;
                d = fminf(fmaxf(d, -2.0f), 2.0f);
                out[idx] = h[idx] + d;
            }
}

extern "C" void kernel_launch(void* const* d_in, const int* in_sizes, int n_in,
                              void* d_out, int out_size, void* d_ws, size_t ws_size,
                              hipStream_t stream) {
    const float* h      = (const float*)d_in[0];
    const int* mask     = (const int*)d_in[1];
    const float* ln_g   = (const float*)d_in[2];
    const float* ln_b   = (const float*)d_in[3];
    const float* W_out  = (const float*)d_in[4];
    const float* W_nm   = (const float*)d_in[5];
    const float* b_nm   = (const float*)d_in[6];
    const float* W_wg   = (const float*)d_in[7];
    const float* b_wg   = (const float*)d_in[8];
    float* out = (float*)d_out;

    char* ws = (char*)d_ws;
    size_t off = 0;
    float* fbuf = (float*)(ws + off);  off += (size_t)BB * TT * NS * 4;          // 8.39 MB
    float* wgbuf = (float*)(ws + off); off += (size_t)BB * TT * 4;
    int* ssbuf = (int*)(ws + off);     off += (size_t)BB * TT * 4;
    float* R = (float*)(ws + off);     off += (size_t)BB * TT * 4;
    float* Q = (float*)(ws + off);     off += (size_t)BB * TT * 4;
    float* P2 = (float*)(ws + off);    off += (size_t)BB * TT * 4;
    float* snap = (float*)(ws + off);  off += (size_t)BB * NCHUNK * NS * DIM * 4; // 29.4 MB
    __hip_bfloat16* Mbuf = (__hip_bfloat16*)(ws + off);
    off += (size_t)BB * TT * DIM * 2;                                             // 58.7 MB

    hipLaunchKernelGGL(k0_dots, dim3(BB * TT), dim3(64), 0, stream,
                       h, W_nm, W_wg, R, Q, P2);
    hipLaunchKernelGGL(k1_scan, dim3(BB), dim3(1024), 0, stream,
                       h, mask, W_wg, b_nm, b_wg, R, Q, P2, fbuf, wgbuf, ssbuf, snap);
    hipLaunchKernelGGL(k2_replay, dim3(BB * NCHUNK), dim3(896), 0, stream,
                       h, fbuf, wgbuf, ssbuf, snap, Mbuf);
    hipLaunchKernelGGL(k3_ln, dim3(BB * TT), dim3(64), 0, stream,
                       Mbuf, ln_g, ln_b);
    hipLaunchKernelGGL(k4_gemm, dim3(7, 256), dim3(256), 0, stream,
                       Mbuf, W_out, h, out);
}

// Round 2
// 7907.202 us; speedup vs baseline: 1.1688x; 1.1688x over previous
//
#include <hip/hip_runtime.h>
#include <hip/hip_bf16.h>

#define DIM 896
#define TT 4096
#define BB 8
#define NS 64           // slots
#define CC 128          // sequential chunk length
#define NC 32           // TT/CC
#define RCH 256         // replay chunk length (k2)
#define NRC 16          // TT/RCH

typedef float floatx4 __attribute__((ext_vector_type(4)));
typedef short short8 __attribute__((ext_vector_type(8)));

// ---------------- K0: per-token dots  R = h.Wnm1, P2 = h.Wnm2, Q = h.Wwg1 ----------------
__global__ __launch_bounds__(64) void k0_dots(const float* __restrict__ h,
                                              const float* __restrict__ W_nm,
                                              const float* __restrict__ W_wg,
                                              float* __restrict__ R, float* __restrict__ Q,
                                              float* __restrict__ P2) {
    const int r = blockIdx.x;
    const int lane = threadIdx.x;
    const float* hr = h + (size_t)r * DIM;
    float a = 0.f, bsum = 0.f, c = 0.f;
    for (int k = lane; k < DIM; k += 64) {
        float hv = hr[k];
        a = fmaf(hv, W_nm[k], a);
        bsum = fmaf(hv, W_nm[DIM + k], bsum);
        c = fmaf(hv, W_wg[k], c);
    }
    #pragma unroll
    for (int off = 32; off; off >>= 1) {
        a += __shfl_xor(a, off);
        bsum += __shfl_xor(bsum, off);
        c += __shfl_xor(c, off);
    }
    if (lane == 0) { R[r] = a; P2[r] = bsum; Q[r] = c; }
}

// ---------------- KG: per-chunk Gram diagonal blocks  G[tau][t'] = h_tau . h_t' ----------
__global__ __launch_bounds__(256) void kG_gram(const float* __restrict__ h,
                                               float* __restrict__ Gd) {
    const int bc = blockIdx.x;            // b*NC + c
    const int b = bc / NC, c = bc % NC;
    const int tid = threadIdx.x;
    const int ti = tid >> 4, tj = tid & 15;
    __shared__ float Hs[128][33];
    float acc[8][8];
    #pragma unroll
    for (int u = 0; u < 8; u++)
        #pragma unroll
        for (int v = 0; v < 8; v++) acc[u][v] = 0.f;
    const size_t hb = (size_t)b * TT * DIM + (size_t)c * CC * DIM;
    for (int kb = 0; kb < 28; ++kb) {
        __syncthreads();
        #pragma unroll
        for (int l = 0; l < 16; ++l) {
            int idx = tid + l * 256;
            int r = idx >> 5, k = idx & 31;
            Hs[r][k] = h[hb + (size_t)r * DIM + kb * 32 + k];
        }
        __syncthreads();
        #pragma unroll 4
        for (int k = 0; k < 32; ++k) {
            float av[8], bv[8];
            #pragma unroll
            for (int u = 0; u < 8; u++) av[u] = Hs[ti * 8 + u][k];
            #pragma unroll
            for (int v = 0; v < 8; v++) bv[v] = Hs[tj * 8 + v][k];
            #pragma unroll
            for (int u = 0; u < 8; u++)
                #pragma unroll
                for (int v = 0; v < 8; v++)
                    acc[u][v] = fmaf(av[u], bv[v], acc[u][v]);
        }
    }
    float* gp = Gd + (size_t)bc * CC * CC;
    #pragma unroll
    for (int u = 0; u < 8; u++)
        #pragma unroll
        for (int v = 0; v < 8; v++)
            gp[(size_t)(ti * 8 + u) * CC + (tj * 8 + v)] = acc[u][v];
}

// ---------------- KB: fused mem-replay (chunk c-1) + Base GEMM for chunk c ---------------
// grid (14, BB): slice = 64-dim K-slice. 256 threads.
#define MC_(i) case i: mc[i] = fmaf(mc[i], om, wh); break;
__global__ __launch_bounds__(256) void kB_base(const float* __restrict__ h,
                                               const float* __restrict__ wgbuf,
                                               const int* __restrict__ ssbuf,
                                               float* __restrict__ memS,
                                               float* __restrict__ snap,
                                               float* __restrict__ Base,
                                               int c) {
    const int slice = blockIdx.x;
    const int b = blockIdx.y;
    const int tid = threadIdx.x;
    __shared__ float wsh[CC];
    __shared__ int   ssh[CC];
    __shared__ float Asb[64][65];     // [k within slice][s]
    __shared__ float Bsb[CC][65];     // [t'][k]

    if (tid < CC) {
        wsh[tid] = wgbuf[b * TT + (c - 1) * CC + tid];
        ssh[tid] = ssbuf[b * TT + (c - 1) * CC + tid];
    }
    const int q = tid >> 6, d = tid & 63;   // q = slot quarter, d = dim within slice
    const int dg = slice * 64 + d;
    float mc[16];
    #pragma unroll
    for (int j = 0; j < 16; j++) mc[j] = memS[((size_t)b * NS + q * 16 + j) * DIM + dg];
    __syncthreads();

    const size_t hb = (size_t)b * TT * DIM + (size_t)((c - 1) * CC) * DIM + dg;
    #pragma unroll 8
    for (int i = 0; i < CC; ++i) {
        float hvv = h[hb + (size_t)i * DIM];
        int ss = ssh[i]; float w = wsh[i];
        if ((ss >> 4) == q) {
            float om = 1.f - w, wh = w * hvv;
            switch (ss & 15) {
                MC_(0) MC_(1) MC_(2) MC_(3) MC_(4) MC_(5) MC_(6) MC_(7)
                MC_(8) MC_(9) MC_(10) MC_(11) MC_(12) MC_(13) MC_(14) MC_(15)
            }
        }
    }
    #pragma unroll
    for (int j = 0; j < 16; j++) {
        memS[((size_t)b * NS + q * 16 + j) * DIM + dg] = mc[j];
        Asb[d][q * 16 + j] = mc[j];
    }
    if ((c & 1) == 0) {
        const int r = c >> 1;
        #pragma unroll
        for (int j = 0; j < 16; j++)
            snap[(((size_t)b * NRC + r) * NS + q * 16 + j) * DIM + dg] = mc[j];
    }
    // stage B tile: h rows of chunk c, this K-slice
    const size_t hb2 = (size_t)b * TT * DIM + (size_t)(c * CC) * DIM + slice * 64;
    for (int idx = tid; idx < CC * 64; idx += 256) {
        int tp = idx >> 6, k = idx & 63;
        Bsb[tp][k] = h[hb2 + (size_t)tp * DIM + k];
    }
    __syncthreads();

    // GEMM: outputs [t' in 128][s in 64], K = 64 (this slice); micro 4 t' x 8 s
    const int tg = tid >> 3, sg = tid & 7;
    float acc[4][8];
    #pragma unroll
    for (int v = 0; v < 4; v++)
        #pragma unroll
        for (int u = 0; u < 8; u++) acc[v][u] = 0.f;
    #pragma unroll 4
    for (int k = 0; k < 64; ++k) {
        float bv[4], av[8];
        #pragma unroll
        for (int v = 0; v < 4; v++) bv[v] = Bsb[tg * 4 + v][k];
        #pragma unroll
        for (int u = 0; u < 8; u++) av[u] = Asb[k][sg * 8 + u];
        #pragma unroll
        for (int v = 0; v < 4; v++)
            #pragma unroll
            for (int u = 0; u < 8; u++)
                acc[v][u] = fmaf(bv[v], av[u], acc[v][u]);
    }
    float* bp = Base + ((size_t)(b * NC) + c) * CC * NS;
    #pragma unroll
    for (int v = 0; v < 4; v++)
        #pragma unroll
        for (int u = 0; u < 8; u++)
            atomicAdd(&bp[(size_t)(tg * 4 + v) * NS + sg * 8 + u], acc[v][u]);
}

// ---------------- KS: sequential scan over one chunk, ONE WAVE per batch -----------------
__global__ __launch_bounds__(64) void kS_seq(const float* __restrict__ Base,
                                             const float* __restrict__ Gd,
                                             const float* __restrict__ Rv,
                                             const float* __restrict__ Qv,
                                             const float* __restrict__ P2v,
                                             const int* __restrict__ mask,
                                             const float* __restrict__ b_nm,
                                             const float* __restrict__ b_wg,
                                             const float* __restrict__ W_wg,
                                             float* __restrict__ Kvec,
                                             float* __restrict__ fbuf,
                                             float* __restrict__ wgbuf,
                                             int* __restrict__ ssbuf,
                                             int c) {
    const int b = blockIdx.x;
    const int lane = threadIdx.x;
    __shared__ float S[CC * 65];     // [t'][s], raw dots, pad 65
    __shared__ float Rl[CC], Ql[CC], Pl[CC], Ml[CC];
    const int t0 = c * CC;

    const float* bp = Base + ((size_t)(b * NC) + c) * CC * NS;
    #pragma unroll 4
    for (int t = 0; t < CC; ++t) S[t * 65 + lane] = bp[(size_t)t * NS + lane];
    for (int i = lane; i < CC; i += 64) {
        Rl[i] = Rv[b * TT + t0 + i];
        Ql[i] = Qv[b * TT + t0 + i];
        Pl[i] = P2v[b * TT + t0 + i];
        Ml[i] = (float)mask[b * TT + t0 + i];
    }
    float K = Kvec[b * NS + lane];
    const float scale = 1.0f / sqrtf((float)DIM);
    const float bnm = b_nm[0], bwg = b_wg[0], wD = W_wg[DIM];
    const float* gdc = Gd + (size_t)(b * NC + c) * CC * CC;

    for (int tau = 0; tau < CC; ++tau) {
        float sc = S[tau * 65 + lane];
        // prefetch G row entries for the eager update (addresses known now)
        int r1 = tau + 1 + lane, r2 = tau + 65 + lane;
        float g0 = (r1 < CC) ? gdc[(size_t)tau * CC + r1] : 0.f;
        float g1 = (r2 < CC) ? gdc[(size_t)tau * CC + r2] : 0.f;
        float sco = sc * scale;
        // chain A: exp + sums (no max-subtraction; |sco| <~ 37, safe in fp32)
        float e = __expf(sco);
        float se = e, sk = e * K;
        // chain B: argmax with lowest-index tie-break (runs concurrently)
        float mv = sco; int mi = lane;
        #pragma unroll
        for (int off = 1; off < 64; off <<= 1) {
            float ov = __shfl_xor(mv, off); int oi = __shfl_xor(mi, off);
            if (ov > mv || (ov == mv && oi < mi)) { mv = ov; mi = oi; }
        }
        #pragma unroll
        for (int off = 1; off < 64; off <<= 1) {
            se += __shfl_xor(se, off);
            sk += __shfl_xor(sk, off);
        }
        float inv = 1.f / se;
        float a = e * inv;
        fbuf[((size_t)b * TT + t0 + tau) * NS + lane] = a;
        float gdot = sk * inv;
        float g = 1.f / (1.f + __expf(-(Rl[tau] + gdot + bnm)));
        float w = 1.f / (1.f + __expf(-(Ql[tau] + g * wD + bwg)));
        w = fminf(w, 0.2f) * Ml[tau];
        if (lane == 0) {
            wgbuf[b * TT + t0 + tau] = w;
            ssbuf[b * TT + t0 + tau] = mi;
        }
        if (lane == mi) K = fmaf(K, 1.f - w, w * Pl[tau]);
        float om = 1.f - w;
        if (r1 < CC) S[r1 * 65 + mi] = fmaf(S[r1 * 65 + mi], om, w * g0);
        if (r2 < CC) S[r2 * 65 + mi] = fmaf(S[r2 * 65 + mi], om, w * g1);
    }
    Kvec[b * NS + lane] = K;
}

// ---------------- K2: chunk-parallel replay -> m_t (bf16) ----------------
#define CS_(i) case i: mem[i] = fmaf(mem[i], sA, aB); break;
__global__ __launch_bounds__(896) void k2_replay(const float* __restrict__ h,
                                                 const float* __restrict__ fbuf,
                                                 const float* __restrict__ wgbuf,
                                                 const int* __restrict__ ssbuf,
                                                 const float* __restrict__ snap,
                                                 __hip_bfloat16* __restrict__ Mbuf) {
    const int blk = blockIdx.x;
    const int b = blk >> 4;
    const int c = blk & 15;
    const int tid = threadIdx.x;   // dim index

    __shared__ float lf[128 * NS];
    __shared__ float lwg[RCH];
    __shared__ int   lss[RCH];

    float mem[64];
    const float* sp = snap + (((size_t)b * NRC + c) * NS) * DIM + tid;
    #pragma unroll
    for (int s2 = 0; s2 < 64; s2++) mem[s2] = sp[(size_t)s2 * DIM];

    const int t0 = c * RCH;
    if (tid < RCH) {
        lwg[tid] = wgbuf[b * TT + t0 + tid];
        lss[tid] = ssbuf[b * TT + t0 + tid];
    }
    const size_t hbase = (size_t)b * TT * DIM + (size_t)t0 * DIM + tid;
    const size_t fbase = ((size_t)b * TT + t0) * NS;
    const size_t mrow = ((size_t)b * TT + t0) * DIM + tid;

    for (int half = 0; half < 2; ++half) {
        __syncthreads();
        for (int idx = tid; idx < 128 * NS; idx += 896)
            lf[idx] = fbuf[fbase + (size_t)half * 128 * NS + idx];
        __syncthreads();
        for (int tl = 0; tl < 128; ++tl) {
            const int tt = half * 128 + tl;
            float hval = h[hbase + (size_t)tt * DIM];
            float m = 0.f;
            const float4* f4p = (const float4*)&lf[tl * NS];
            #pragma unroll
            for (int qq = 0; qq < 16; qq++) {
                float4 f4 = f4p[qq];
                m = fmaf(f4.x, mem[4 * qq], m);
                m = fmaf(f4.y, mem[4 * qq + 1], m);
                m = fmaf(f4.z, mem[4 * qq + 2], m);
                m = fmaf(f4.w, mem[4 * qq + 3], m);
            }
            Mbuf[mrow + (size_t)tt * DIM] = __float2bfloat16(m);
            float w = lwg[tt];
            int ss = lss[tt];
            float sA = 1.0f - w, aB = w * hval;
            switch (ss) {
                CS_(0) CS_(1) CS_(2) CS_(3) CS_(4) CS_(5) CS_(6) CS_(7)
                CS_(8) CS_(9) CS_(10) CS_(11) CS_(12) CS_(13) CS_(14) CS_(15)
                CS_(16) CS_(17) CS_(18) CS_(19) CS_(20) CS_(21) CS_(22) CS_(23)
                CS_(24) CS_(25) CS_(26) CS_(27) CS_(28) CS_(29) CS_(30) CS_(31)
                CS_(32) CS_(33) CS_(34) CS_(35) CS_(36) CS_(37) CS_(38) CS_(39)
                CS_(40) CS_(41) CS_(42) CS_(43) CS_(44) CS_(45) CS_(46) CS_(47)
                CS_(48) CS_(49) CS_(50) CS_(51) CS_(52) CS_(53) CS_(54) CS_(55)
                CS_(56) CS_(57) CS_(58) CS_(59) CS_(60) CS_(61) CS_(62) CS_(63)
            }
        }
    }
}

// ---------------- K3: row LayerNorm in place on Mbuf (bf16) ----------------
__global__ __launch_bounds__(64) void k3_ln(__hip_bfloat16* __restrict__ Mbuf,
                                            const float* __restrict__ ln_g,
                                            const float* __restrict__ ln_b) {
    const size_t r = blockIdx.x;
    const int lane = threadIdx.x;
    __hip_bfloat16* row = Mbuf + r * DIM;
    float v[14];
    float s1 = 0.f, s2 = 0.f;
    #pragma unroll
    for (int i = 0; i < 14; i++) {
        float x = __bfloat162float(row[lane + 64 * i]);
        v[i] = x; s1 += x; s2 = fmaf(x, x, s2);
    }
    #pragma unroll
    for (int off = 32; off; off >>= 1) {
        s1 += __shfl_xor(s1, off);
        s2 += __shfl_xor(s2, off);
    }
    float mu = s1 * (1.0f / DIM);
    float var = fmaxf(s2 * (1.0f / DIM) - mu * mu, 0.0f);
    float rs = 1.0f / sqrtf(var + 1e-5f);
    #pragma unroll
    for (int i = 0; i < 14; i++) {
        int d = lane + 64 * i;
        row[d] = __float2bfloat16((v[i] - mu) * rs * ln_g[d] + ln_b[d]);
    }
}

// ---------------- K4: out = h + clip(0.5 * MN @ W_out^T) (bf16 MFMA GEMM) ----------------
__global__ __launch_bounds__(256) void k4_gemm(const __hip_bfloat16* __restrict__ Mn,
                                               const float* __restrict__ W_out,
                                               const float* __restrict__ h,
                                               float* __restrict__ out) {
    const int nt = blockIdx.x;   // 0..6
    const int mt = blockIdx.y;   // 0..255
    const int tid = threadIdx.x;
    const int wave = tid >> 6, lane = tid & 63;
    const int wr = wave >> 1, wc = wave & 1;

    __shared__ __hip_bfloat16 Asb[128 * 72];
    __shared__ __hip_bfloat16 Bsb[128 * 72];

    floatx4 acc[4][4];
    #pragma unroll
    for (int i = 0; i < 4; i++)
        #pragma unroll
        for (int jn = 0; jn < 4; jn++)
            acc[i][jn] = (floatx4){0.f, 0.f, 0.f, 0.f};

    const int lrow = lane & 15;
    const int lk = (lane >> 4) * 8;
    const int rr = tid >> 3, ch = tid & 7;

    for (int kt = 0; kt < 14; ++kt) {
        #pragma unroll
        for (int it = 0; it < 4; ++it) {
            int row = rr + 32 * it;
            const uint4* srcA = (const uint4*)(Mn + ((size_t)(mt * 128 + row)) * DIM + kt * 64 + ch * 8);
            *(uint4*)&Asb[row * 72 + ch * 8] = *srcA;
            const float* srcB = W_out + ((size_t)(nt * 128 + row)) * DIM + kt * 64 + ch * 8;
            float4 f0 = *(const float4*)srcB;
            float4 f1 = *(const float4*)(srcB + 4);
            alignas(16) __hip_bfloat16 tmp[8];
            tmp[0] = __float2bfloat16(f0.x); tmp[1] = __float2bfloat16(f0.y);
            tmp[2] = __float2bfloat16(f0.z); tmp[3] = __float2bfloat16(f0.w);
            tmp[4] = __float2bfloat16(f1.x); tmp[5] = __float2bfloat16(f1.y);
            tmp[6] = __float2bfloat16(f1.z); tmp[7] = __float2bfloat16(f1.w);
            *(uint4*)&Bsb[row * 72 + ch * 8] = *(uint4*)tmp;
        }
        __syncthreads();
        #pragma unroll
        for (int kk = 0; kk < 2; ++kk) {
            short8 af[4], bfr[4];
            #pragma unroll
            for (int i = 0; i < 4; i++)
                af[i] = *(const short8*)&Asb[(wr * 64 + i * 16 + lrow) * 72 + kk * 32 + lk];
            #pragma unroll
            for (int i2 = 0; i2 < 4; i2++)
                bfr[i2] = *(const short8*)&Bsb[(wc * 64 + i2 * 16 + lrow) * 72 + kk * 32 + lk];
            #pragma unroll
            for (int i = 0; i < 4; i++)
                #pragma unroll
                for (int jn = 0; jn < 4; jn++)
                    acc[i][jn] = __builtin_amdgcn_mfma_f32_16x16x32_bf16(af[i], bfr[jn], acc[i][jn], 0, 0, 0);
        }
        __syncthreads();
    }
    const int crow = (lane >> 4) * 4, ccol = lane & 15;
    #pragma unroll
    for (int i = 0; i < 4; i++)
        #pragma unroll
        for (int jn = 0; jn < 4; jn++)
            #pragma unroll
            for (int rg = 0; rg < 4; rg++) {
                int rG = mt * 128 + wr * 64 + i * 16 + crow + rg;
                int nG = nt * 128 + wc * 64 + jn * 16 + ccol;
                size_t idx = (size_t)rG * DIM + nG;
                float d = acc[i][jn][rg] * 0.5f;
                d = fminf(fmaxf(d, -2.0f), 2.0f);
                out[idx] = h[idx] + d;
            }
}

extern "C" void kernel_launch(void* const* d_in, const int* in_sizes, int n_in,
                              void* d_out, int out_size, void* d_ws, size_t ws_size,
                              hipStream_t stream) {
    const float* h      = (const float*)d_in[0];
    const int* mask     = (const int*)d_in[1];
    const float* ln_g   = (const float*)d_in[2];
    const float* ln_b   = (const float*)d_in[3];
    const float* W_out  = (const float*)d_in[4];
    const float* W_nm   = (const float*)d_in[5];
    const float* b_nm   = (const float*)d_in[6];
    const float* W_wg   = (const float*)d_in[7];
    const float* b_wg   = (const float*)d_in[8];
    float* out = (float*)d_out;

    char* ws = (char*)d_ws;
    // ---- zeroed region ----
    float* Base  = (float*)(ws);                                   // 8,388,608 B
    float* memS  = (float*)(ws + 8388608);                         // 1,835,008 B
    float* Kvec  = (float*)(ws + 8388608 + 1835008);               // 2,048 B
    float* snap  = (float*)(ws + 8388608 + 1835008 + 2048);        // 29,360,128 B
    const size_t ZBYTES = 8388608 + 1835008 + 2048 + 29360128;     // 39,585,792
    // ---- non-zeroed ----
    float* fbuf  = (float*)(ws + ZBYTES);                          // 8,388,608
    float* wgbuf = (float*)(ws + ZBYTES + 8388608);                // 131,072
    int*   ssbuf = (int*)  (ws + ZBYTES + 8388608 + 131072);       // 131,072
    char*  Mreg  = ws + ZBYTES + 8388608 + 262144;                 // 58,720,256 region
    // phase-1 buffers aliased inside the Mbuf region (dead before k2 writes Mbuf)
    float* Gd = (float*)(Mreg);                                    // 16,777,216
    float* R  = (float*)(Mreg + 16777216);
    float* Q  = (float*)(Mreg + 16777216 + 131072);
    float* P2 = (float*)(Mreg + 16777216 + 262144);
    __hip_bfloat16* Mbuf = (__hip_bfloat16*)Mreg;

    hipMemsetAsync(ws, 0, ZBYTES, stream);
    hipLaunchKernelGGL(k0_dots, dim3(BB * TT), dim3(64), 0, stream,
                       h, W_nm, W_wg, R, Q, P2);
    hipLaunchKernelGGL(kG_gram, dim3(BB * NC), dim3(256), 0, stream, h, Gd);

    hipLaunchKernelGGL(kS_seq, dim3(BB), dim3(64), 0, stream,
                       Base, Gd, R, Q, P2, mask, b_nm, b_wg, W_wg,
                       Kvec, fbuf, wgbuf, ssbuf, 0);
    for (int c = 1; c < NC; ++c) {
        hipLaunchKernelGGL(kB_base, dim3(14, BB), dim3(256), 0, stream,
                           h, wgbuf, ssbuf, memS, snap, Base, c);
        hipLaunchKernelGGL(kS_seq, dim3(BB), dim3(64), 0, stream,
                           Base, Gd, R, Q, P2, mask, b_nm, b_wg, W_wg,
                           Kvec, fbuf, wgbuf, ssbuf, c);
    }

    hipLaunchKernelGGL(k2_replay, dim3(BB * NRC), dim3(896), 0, stream,
                       h, fbuf, wgbuf, ssbuf, snap, Mbuf);
    hipLaunchKernelGGL(k3_ln, dim3(BB * TT), dim3(64), 0, stream,
                       Mbuf, ln_g, ln_b);
    hipLaunchKernelGGL(k4_gemm, dim3(7, 256), dim3(256), 0, stream,
                       Mbuf, W_out, h, out);
}

// Round 3
// 6295.018 us; speedup vs baseline: 1.4682x; 1.2561x over previous
//
#include <hip/hip_runtime.h>
#include <hip/hip_bf16.h>

#define DIM 896
#define TT 4096
#define BB 8
#define NS 64           // slots
#define CC 128          // sequential chunk length
#define NC 32           // TT/CC
#define RCH 256         // replay chunk length (k2)
#define NRC 16          // TT/RCH

typedef float floatx4 __attribute__((ext_vector_type(4)));
typedef short short8 __attribute__((ext_vector_type(8)));

// -------- DPP wave64 reductions (VALU, no DS pipe) --------
#define DPP_F(x_, ctrl_, rmask_, old_) \
  __int_as_float(__builtin_amdgcn_update_dpp(__float_as_int(old_), __float_as_int(x_), (ctrl_), (rmask_), 0xf, false))

__device__ __forceinline__ float wave_sum64(float x) {
    x += DPP_F(x, 0x111, 0xf, 0.0f);   // row_shr:1
    x += DPP_F(x, 0x112, 0xf, 0.0f);   // row_shr:2
    x += DPP_F(x, 0x114, 0xf, 0.0f);   // row_shr:4
    x += DPP_F(x, 0x118, 0xf, 0.0f);   // row_shr:8
    x += DPP_F(x, 0x142, 0xa, 0.0f);   // row_bcast:15 -> rows 1,3
    x += DPP_F(x, 0x143, 0xc, 0.0f);   // row_bcast:31 -> rows 2,3
    return __int_as_float(__builtin_amdgcn_readlane(__float_as_int(x), 63));
}
__device__ __forceinline__ float wave_max64(float x) {
    x = fmaxf(x, DPP_F(x, 0x111, 0xf, -INFINITY));
    x = fmaxf(x, DPP_F(x, 0x112, 0xf, -INFINITY));
    x = fmaxf(x, DPP_F(x, 0x114, 0xf, -INFINITY));
    x = fmaxf(x, DPP_F(x, 0x118, 0xf, -INFINITY));
    x = fmaxf(x, DPP_F(x, 0x142, 0xa, -INFINITY));
    x = fmaxf(x, DPP_F(x, 0x143, 0xc, -INFINITY));
    return __int_as_float(__builtin_amdgcn_readlane(__float_as_int(x), 63));
}

// ---------------- K0: per-token dots  R = h.Wnm1, P2 = h.Wnm2, Q = h.Wwg1 ----------------
__global__ __launch_bounds__(64) void k0_dots(const float* __restrict__ h,
                                              const float* __restrict__ W_nm,
                                              const float* __restrict__ W_wg,
                                              float* __restrict__ R, float* __restrict__ Q,
                                              float* __restrict__ P2) {
    const int r = blockIdx.x;
    const int lane = threadIdx.x;
    const float* hr = h + (size_t)r * DIM;
    float a = 0.f, bsum = 0.f, c = 0.f;
    for (int k = lane; k < DIM; k += 64) {
        float hv = hr[k];
        a = fmaf(hv, W_nm[k], a);
        bsum = fmaf(hv, W_nm[DIM + k], bsum);
        c = fmaf(hv, W_wg[k], c);
    }
    #pragma unroll
    for (int off = 32; off; off >>= 1) {
        a += __shfl_xor(a, off);
        bsum += __shfl_xor(bsum, off);
        c += __shfl_xor(c, off);
    }
    if (lane == 0) { R[r] = a; P2[r] = bsum; Q[r] = c; }
}

// ---------------- KG: per-chunk Gram diagonal blocks  G[tau][t'] = h_tau . h_t' ----------
__global__ __launch_bounds__(256) void kG_gram(const float* __restrict__ h,
                                               float* __restrict__ Gd) {
    const int bc = blockIdx.x;            // b*NC + c
    const int b = bc / NC, c = bc % NC;
    const int tid = threadIdx.x;
    const int ti = tid >> 4, tj = tid & 15;
    __shared__ float Hs[128][33];
    float acc[8][8];
    #pragma unroll
    for (int u = 0; u < 8; u++)
        #pragma unroll
        for (int v = 0; v < 8; v++) acc[u][v] = 0.f;
    const size_t hb = (size_t)b * TT * DIM + (size_t)c * CC * DIM;
    for (int kb = 0; kb < 28; ++kb) {
        __syncthreads();
        #pragma unroll
        for (int l = 0; l < 16; ++l) {
            int idx = tid + l * 256;
            int r = idx >> 5, k = idx & 31;
            Hs[r][k] = h[hb + (size_t)r * DIM + kb * 32 + k];
        }
        __syncthreads();
        #pragma unroll 4
        for (int k = 0; k < 32; ++k) {
            float av[8], bv[8];
            #pragma unroll
            for (int u = 0; u < 8; u++) av[u] = Hs[ti * 8 + u][k];
            #pragma unroll
            for (int v = 0; v < 8; v++) bv[v] = Hs[tj * 8 + v][k];
            #pragma unroll
            for (int u = 0; u < 8; u++)
                #pragma unroll
                for (int v = 0; v < 8; v++)
                    acc[u][v] = fmaf(av[u], bv[v], acc[u][v]);
        }
    }
    float* gp = Gd + (size_t)bc * CC * CC;
    #pragma unroll
    for (int u = 0; u < 8; u++)
        #pragma unroll
        for (int v = 0; v < 8; v++)
            gp[(size_t)(ti * 8 + u) * CC + (tj * 8 + v)] = acc[u][v];
}

// ---------------- KB: fused mem-replay (chunk c-1) + Base GEMM for chunk c ---------------
#define MC_(i) case i: mc[i] = fmaf(mc[i], om, wh); break;
__global__ __launch_bounds__(256) void kB_base(const float* __restrict__ h,
                                               const float* __restrict__ wgbuf,
                                               const int* __restrict__ ssbuf,
                                               float* __restrict__ memS,
                                               float* __restrict__ snap,
                                               float* __restrict__ Base,
                                               int c) {
    const int slice = blockIdx.x;
    const int b = blockIdx.y;
    const int tid = threadIdx.x;
    __shared__ float wsh[CC];
    __shared__ int   ssh[CC];
    __shared__ float Asb[64][65];     // [k within slice][s]
    __shared__ float Bsb[CC][65];     // [t'][k]

    if (tid < CC) {
        wsh[tid] = wgbuf[b * TT + (c - 1) * CC + tid];
        ssh[tid] = ssbuf[b * TT + (c - 1) * CC + tid];
    }
    const int q = tid >> 6, d = tid & 63;
    const int dg = slice * 64 + d;
    float mc[16];
    #pragma unroll
    for (int j = 0; j < 16; j++) mc[j] = memS[((size_t)b * NS + q * 16 + j) * DIM + dg];
    __syncthreads();

    const size_t hb = (size_t)b * TT * DIM + (size_t)((c - 1) * CC) * DIM + dg;
    #pragma unroll 8
    for (int i = 0; i < CC; ++i) {
        float hvv = h[hb + (size_t)i * DIM];
        int ss = ssh[i]; float w = wsh[i];
        if ((ss >> 4) == q) {
            float om = 1.f - w, wh = w * hvv;
            switch (ss & 15) {
                MC_(0) MC_(1) MC_(2) MC_(3) MC_(4) MC_(5) MC_(6) MC_(7)
                MC_(8) MC_(9) MC_(10) MC_(11) MC_(12) MC_(13) MC_(14) MC_(15)
            }
        }
    }
    #pragma unroll
    for (int j = 0; j < 16; j++) {
        memS[((size_t)b * NS + q * 16 + j) * DIM + dg] = mc[j];
        Asb[d][q * 16 + j] = mc[j];
    }
    if ((c & 1) == 0) {
        const int r = c >> 1;
        #pragma unroll
        for (int j = 0; j < 16; j++)
            snap[(((size_t)b * NRC + r) * NS + q * 16 + j) * DIM + dg] = mc[j];
    }
    const size_t hb2 = (size_t)b * TT * DIM + (size_t)(c * CC) * DIM + slice * 64;
    for (int idx = tid; idx < CC * 64; idx += 256) {
        int tp = idx >> 6, k = idx & 63;
        Bsb[tp][k] = h[hb2 + (size_t)tp * DIM + k];
    }
    __syncthreads();

    const int tg = tid >> 3, sg = tid & 7;
    float acc[4][8];
    #pragma unroll
    for (int v = 0; v < 4; v++)
        #pragma unroll
        for (int u = 0; u < 8; u++) acc[v][u] = 0.f;
    #pragma unroll 4
    for (int k = 0; k < 64; ++k) {
        float bv[4], av[8];
        #pragma unroll
        for (int v = 0; v < 4; v++) bv[v] = Bsb[tg * 4 + v][k];
        #pragma unroll
        for (int u = 0; u < 8; u++) av[u] = Asb[k][sg * 8 + u];
        #pragma unroll
        for (int v = 0; v < 4; v++)
            #pragma unroll
            for (int u = 0; u < 8; u++)
                acc[v][u] = fmaf(bv[v], av[u], acc[v][u]);
    }
    float* bp = Base + ((size_t)(b * NC) + c) * CC * NS;
    #pragma unroll
    for (int v = 0; v < 4; v++)
        #pragma unroll
        for (int u = 0; u < 8; u++)
            atomicAdd(&bp[(size_t)(tg * 4 + v) * NS + sg * 8 + u], acc[v][u]);
}

// ---------------- KS: sequential scan over one chunk, ONE WAVE per batch -----------------
// DPP reductions + ballot argmax + register-rotated S row with scalar fixup.
__global__ __launch_bounds__(64) void kS_seq(const float* __restrict__ Base,
                                             const float* __restrict__ Gd,
                                             const float* __restrict__ Rv,
                                             const float* __restrict__ Qv,
                                             const float* __restrict__ P2v,
                                             const int* __restrict__ mask,
                                             const float* __restrict__ b_nm,
                                             const float* __restrict__ b_wg,
                                             const float* __restrict__ W_wg,
                                             float* __restrict__ Kvec,
                                             float* __restrict__ fbuf,
                                             float* __restrict__ wgbuf,
                                             int* __restrict__ ssbuf,
                                             int c) {
    const int b = blockIdx.x;
    const int lane = threadIdx.x;
    __shared__ float S[CC * 65];     // [t'][s], raw dots, pad 65
    const int t0 = c * CC;
    const int tb = b * TT + t0;

    const float* bp = Base + ((size_t)(b * NC) + c) * CC * NS;
    #pragma unroll 4
    for (int t = 0; t < CC; ++t) S[t * 65 + lane] = bp[(size_t)t * NS + lane];

    float K = Kvec[b * NS + lane];
    const float scale = 1.0f / sqrtf((float)DIM);
    const float bnm = b_nm[0], bwg = b_wg[0], wD = W_wg[DIM];
    const float* gdc = Gd + (size_t)(b * NC + c) * CC * CC;

    // prefetch step-0 data
    float sc = S[lane];
    float g0 = (1 + lane < CC) ? gdc[1 + lane] : 0.f;
    float g1 = (65 + lane < CC) ? gdc[65 + lane] : 0.f;
    float Rt = Rv[tb], Qt = Qv[tb], Pt = P2v[tb];
    float Mk = (float)mask[tb];

    for (int tau = 0; tau < CC; ++tau) {
        const int tn = tau + 1;
        // ---- prefetch next-step data (pre-update S row; fixed up in-register below) ----
        float sc_n = 0.f, g0n = 0.f, g1n = 0.f, Rn = 0.f, Qn = 0.f, Pn = 0.f, Mn_ = 0.f;
        if (tn < CC) {
            sc_n = S[tn * 65 + lane];
            int r1n = tn + 1 + lane, r2n = tn + 65 + lane;
            if (r1n < CC) g0n = gdc[(size_t)tn * CC + r1n];
            if (r2n < CC) g1n = gdc[(size_t)tn * CC + r2n];
            Rn = Rv[tb + tn]; Qn = Qv[tb + tn]; Pn = P2v[tb + tn];
            Mn_ = (float)mask[tb + tn];
        }
        float gself = __int_as_float(__builtin_amdgcn_readlane(__float_as_int(g0), 0)); // G[tau][tau+1]

        float sco = sc * scale;
        // reductions: max (argmax via ballot), sum(e), sum(e*K) — all VALU DPP
        float mv = wave_max64(sco);
        float e = __expf(sco);
        float se = wave_sum64(e);
        float sk = wave_sum64(e * K);
        unsigned long long bal = __ballot(sco == mv);
        int mi = (int)__ffsll(bal) - 1;                 // lowest-index tie-break (sgpr)

        float inv = 1.f / se;
        fbuf[((size_t)tb + tau) * NS + lane] = e * inv; // attn row
        float gdot = sk * inv;
        float g = 1.f / (1.f + __expf(-(Rt + gdot + bnm)));
        float w = 1.f / (1.f + __expf(-(Qt + g * wD + bwg)));
        w = fminf(w, 0.2f) * Mk;
        if (lane == 0) {
            wgbuf[tb + tau] = w;
            ssbuf[tb + tau] = mi;
        }
        float om = 1.f - w;
        K = (lane == mi) ? fmaf(K, om, w * Pt) : K;

        // LDS RMW for future rows at column mi (off critical path)
        int r1 = tau + 1 + lane, r2 = tau + 65 + lane;
        if (r1 < CC) S[r1 * 65 + mi] = fmaf(S[r1 * 65 + mi], om, w * g0);
        if (r2 < CC) S[r2 * 65 + mi] = fmaf(S[r2 * 65 + mi], om, w * g1);

        // register fixup of prefetched next row (column mi only)
        sc = (lane == mi) ? fmaf(sc_n, om, w * gself) : sc_n;
        g0 = g0n; g1 = g1n; Rt = Rn; Qt = Qn; Pt = Pn; Mk = Mn_;
    }
    Kvec[b * NS + lane] = K;
}

// ---------------- K2: chunk-parallel replay -> m_t (bf16) ----------------
#define CS_(i) case i: mem[i] = fmaf(mem[i], sA, aB); break;
__global__ __launch_bounds__(896) void k2_replay(const float* __restrict__ h,
                                                 const float* __restrict__ fbuf,
                                                 const float* __restrict__ wgbuf,
                                                 const int* __restrict__ ssbuf,
                                                 const float* __restrict__ snap,
                                                 __hip_bfloat16* __restrict__ Mbuf) {
    const int blk = blockIdx.x;
    const int b = blk >> 4;
    const int c = blk & 15;
    const int tid = threadIdx.x;   // dim index

    __shared__ float lf[128 * NS];
    __shared__ float lwg[RCH];
    __shared__ int   lss[RCH];

    float mem[64];
    const float* sp = snap + (((size_t)b * NRC + c) * NS) * DIM + tid;
    #pragma unroll
    for (int s2 = 0; s2 < 64; s2++) mem[s2] = sp[(size_t)s2 * DIM];

    const int t0 = c * RCH;
    if (tid < RCH) {
        lwg[tid] = wgbuf[b * TT + t0 + tid];
        lss[tid] = ssbuf[b * TT + t0 + tid];
    }
    const size_t hbase = (size_t)b * TT * DIM + (size_t)t0 * DIM + tid;
    const size_t fbase = ((size_t)b * TT + t0) * NS;
    const size_t mrow = ((size_t)b * TT + t0) * DIM + tid;

    for (int half = 0; half < 2; ++half) {
        __syncthreads();
        for (int idx = tid; idx < 128 * NS; idx += 896)
            lf[idx] = fbuf[fbase + (size_t)half * 128 * NS + idx];
        __syncthreads();
        for (int tl = 0; tl < 128; ++tl) {
            const int tt = half * 128 + tl;
            float hval = h[hbase + (size_t)tt * DIM];
            float m = 0.f;
            const float4* f4p = (const float4*)&lf[tl * NS];
            #pragma unroll
            for (int qq = 0; qq < 16; qq++) {
                float4 f4 = f4p[qq];
                m = fmaf(f4.x, mem[4 * qq], m);
                m = fmaf(f4.y, mem[4 * qq + 1], m);
                m = fmaf(f4.z, mem[4 * qq + 2], m);
                m = fmaf(f4.w, mem[4 * qq + 3], m);
            }
            Mbuf[mrow + (size_t)tt * DIM] = __float2bfloat16(m);
            float w = lwg[tt];
            int ss = lss[tt];
            float sA = 1.0f - w, aB = w * hval;
            switch (ss) {
                CS_(0) CS_(1) CS_(2) CS_(3) CS_(4) CS_(5) CS_(6) CS_(7)
                CS_(8) CS_(9) CS_(10) CS_(11) CS_(12) CS_(13) CS_(14) CS_(15)
                CS_(16) CS_(17) CS_(18) CS_(19) CS_(20) CS_(21) CS_(22) CS_(23)
                CS_(24) CS_(25) CS_(26) CS_(27) CS_(28) CS_(29) CS_(30) CS_(31)
                CS_(32) CS_(33) CS_(34) CS_(35) CS_(36) CS_(37) CS_(38) CS_(39)
                CS_(40) CS_(41) CS_(42) CS_(43) CS_(44) CS_(45) CS_(46) CS_(47)
                CS_(48) CS_(49) CS_(50) CS_(51) CS_(52) CS_(53) CS_(54) CS_(55)
                CS_(56) CS_(57) CS_(58) CS_(59) CS_(60) CS_(61) CS_(62) CS_(63)
            }
        }
    }
}

// ---------------- K3: row LayerNorm in place on Mbuf (bf16) ----------------
__global__ __launch_bounds__(64) void k3_ln(__hip_bfloat16* __restrict__ Mbuf,
                                            const float* __restrict__ ln_g,
                                            const float* __restrict__ ln_b) {
    const size_t r = blockIdx.x;
    const int lane = threadIdx.x;
    __hip_bfloat16* row = Mbuf + r * DIM;
    float v[14];
    float s1 = 0.f, s2 = 0.f;
    #pragma unroll
    for (int i = 0; i < 14; i++) {
        float x = __bfloat162float(row[lane + 64 * i]);
        v[i] = x; s1 += x; s2 = fmaf(x, x, s2);
    }
    #pragma unroll
    for (int off = 32; off; off >>= 1) {
        s1 += __shfl_xor(s1, off);
        s2 += __shfl_xor(s2, off);
    }
    float mu = s1 * (1.0f / DIM);
    float var = fmaxf(s2 * (1.0f / DIM) - mu * mu, 0.0f);
    float rs = 1.0f / sqrtf(var + 1e-5f);
    #pragma unroll
    for (int i = 0; i < 14; i++) {
        int d = lane + 64 * i;
        row[d] = __float2bfloat16((v[i] - mu) * rs * ln_g[d] + ln_b[d]);
    }
}

// ---------------- K4: out = h + clip(0.5 * MN @ W_out^T) (bf16 MFMA GEMM) ----------------
__global__ __launch_bounds__(256) void k4_gemm(const __hip_bfloat16* __restrict__ Mn,
                                               const float* __restrict__ W_out,
                                               const float* __restrict__ h,
                                               float* __restrict__ out) {
    const int nt = blockIdx.x;   // 0..6
    const int mt = blockIdx.y;   // 0..255
    const int tid = threadIdx.x;
    const int wave = tid >> 6, lane = tid & 63;
    const int wr = wave >> 1, wc = wave & 1;

    __shared__ __hip_bfloat16 Asb[128 * 72];
    __shared__ __hip_bfloat16 Bsb[128 * 72];

    floatx4 acc[4][4];
    #pragma unroll
    for (int i = 0; i < 4; i++)
        #pragma unroll
        for (int jn = 0; jn < 4; jn++)
            acc[i][jn] = (floatx4){0.f, 0.f, 0.f, 0.f};

    const int lrow = lane & 15;
    const int lk = (lane >> 4) * 8;
    const int rr = tid >> 3, ch = tid & 7;

    for (int kt = 0; kt < 14; ++kt) {
        #pragma unroll
        for (int it = 0; it < 4; ++it) {
            int row = rr + 32 * it;
            const uint4* srcA = (const uint4*)(Mn + ((size_t)(mt * 128 + row)) * DIM + kt * 64 + ch * 8);
            *(uint4*)&Asb[row * 72 + ch * 8] = *srcA;
            const float* srcB = W_out + ((size_t)(nt * 128 + row)) * DIM + kt * 64 + ch * 8;
            float4 f0 = *(const float4*)srcB;
            float4 f1 = *(const float4*)(srcB + 4);
            alignas(16) __hip_bfloat16 tmp[8];
            tmp[0] = __float2bfloat16(f0.x); tmp[1] = __float2bfloat16(f0.y);
            tmp[2] = __float2bfloat16(f0.z); tmp[3] = __float2bfloat16(f0.w);
            tmp[4] = __float2bfloat16(f1.x); tmp[5] = __float2bfloat16(f1.y);
            tmp[6] = __float2bfloat16(f1.z); tmp[7] = __float2bfloat16(f1.w);
            *(uint4*)&Bsb[row * 72 + ch * 8] = *(uint4*)tmp;
        }
        __syncthreads();
        #pragma unroll
        for (int kk = 0; kk < 2; ++kk) {
            short8 af[4], bfr[4];
            #pragma unroll
            for (int i = 0; i < 4; i++)
                af[i] = *(const short8*)&Asb[(wr * 64 + i * 16 + lrow) * 72 + kk * 32 + lk];
            #pragma unroll
            for (int i2 = 0; i2 < 4; i2++)
                bfr[i2] = *(const short8*)&Bsb[(wc * 64 + i2 * 16 + lrow) * 72 + kk * 32 + lk];
            #pragma unroll
            for (int i = 0; i < 4; i++)
                #pragma unroll
                for (int jn = 0; jn < 4; jn++)
                    acc[i][jn] = __builtin_amdgcn_mfma_f32_16x16x32_bf16(af[i], bfr[jn], acc[i][jn], 0, 0, 0);
        }
        __syncthreads();
    }
    const int crow = (lane >> 4) * 4, ccol = lane & 15;
    #pragma unroll
    for (int i = 0; i < 4; i++)
        #pragma unroll
        for (int jn = 0; jn < 4; jn++)
            #pragma unroll
            for (int rg = 0; rg < 4; rg++) {
                int rG = mt * 128 + wr * 64 + i * 16 + crow + rg;
                int nG = nt * 128 + wc * 64 + jn * 16 + ccol;
                size_t idx = (size_t)rG * DIM + nG;
                float d = acc[i][jn][rg] * 0.5f;
                d = fminf(fmaxf(d, -2.0f), 2.0f);
                out[idx] = h[idx] + d;
            }
}

extern "C" void kernel_launch(void* const* d_in, const int* in_sizes, int n_in,
                              void* d_out, int out_size, void* d_ws, size_t ws_size,
                              hipStream_t stream) {
    const float* h      = (const float*)d_in[0];
    const int* mask     = (const int*)d_in[1];
    const float* ln_g   = (const float*)d_in[2];
    const float* ln_b   = (const float*)d_in[3];
    const float* W_out  = (const float*)d_in[4];
    const float* W_nm   = (const float*)d_in[5];
    const float* b_nm   = (const float*)d_in[6];
    const float* W_wg   = (const float*)d_in[7];
    const float* b_wg   = (const float*)d_in[8];
    float* out = (float*)d_out;

    char* ws = (char*)d_ws;
    // ---- zeroed region ----
    float* Base  = (float*)(ws);                                   // 8,388,608 B
    float* memS  = (float*)(ws + 8388608);                         // 1,835,008 B
    float* Kvec  = (float*)(ws + 8388608 + 1835008);               // 2,048 B
    float* snap  = (float*)(ws + 8388608 + 1835008 + 2048);        // 29,360,128 B
    const size_t ZBYTES = 8388608 + 1835008 + 2048 + 29360128;     // 39,585,792
    // ---- non-zeroed ----
    float* fbuf  = (float*)(ws + ZBYTES);                          // 8,388,608
    float* wgbuf = (float*)(ws + ZBYTES + 8388608);                // 131,072
    int*   ssbuf = (int*)  (ws + ZBYTES + 8388608 + 131072);       // 131,072
    char*  Mreg  = ws + ZBYTES + 8388608 + 262144;                 // 58,720,256 region
    float* Gd = (float*)(Mreg);                                    // 16,777,216
    float* R  = (float*)(Mreg + 16777216);
    float* Q  = (float*)(Mreg + 16777216 + 131072);
    float* P2 = (float*)(Mreg + 16777216 + 262144);
    __hip_bfloat16* Mbuf = (__hip_bfloat16*)Mreg;

    hipMemsetAsync(ws, 0, ZBYTES, stream);
    hipLaunchKernelGGL(k0_dots, dim3(BB * TT), dim3(64), 0, stream,
                       h, W_nm, W_wg, R, Q, P2);
    hipLaunchKernelGGL(kG_gram, dim3(BB * NC), dim3(256), 0, stream, h, Gd);

    hipLaunchKernelGGL(kS_seq, dim3(BB), dim3(64), 0, stream,
                       Base, Gd, R, Q, P2, mask, b_nm, b_wg, W_wg,
                       Kvec, fbuf, wgbuf, ssbuf, 0);
    for (int c = 1; c < NC; ++c) {
        hipLaunchKernelGGL(kB_base, dim3(14, BB), dim3(256), 0, stream,
                           h, wgbuf, ssbuf, memS, snap, Base, c);
        hipLaunchKernelGGL(kS_seq, dim3(BB), dim3(64), 0, stream,
                           Base, Gd, R, Q, P2, mask, b_nm, b_wg, W_wg,
                           Kvec, fbuf, wgbuf, ssbuf, c);
    }

    hipLaunchKernelGGL(k2_replay, dim3(BB * NRC), dim3(896), 0, stream,
                       h, fbuf, wgbuf, ssbuf, snap, Mbuf);
    hipLaunchKernelGGL(k3_ln, dim3(BB * TT), dim3(64), 0, stream,
                       Mbuf, ln_g, ln_b);
    hipLaunchKernelGGL(k4_gemm, dim3(7, 256), dim3(256), 0, stream,
                       Mbuf, W_out, h, out);
}